// Round 5
// baseline (247.939 us; speedup 1.0000x reference)
//
#include <hip/hip_runtime.h>
#include <math.h>

#define CC 256
#define HEADS 8
#define DD 32
#define GG 48
#define LL (GG*GG)      // 2304
#define NB 2
#define PTAB_N 95
#define KVH 1152        // kv rows per half

typedef float f32x4 __attribute__((ext_vector_type(4)));
typedef __bf16 bf16x8 __attribute__((ext_vector_type(8)));
typedef __bf16 bf16x4 __attribute__((ext_vector_type(4)));

// workspace layout (floats).
// pao1 aliases xs (xs dead after gemm_qv/eb; po also aliases xs, written after comb).
#define OFF_XS   0
#define SZ_XS    (NB*CC*LL)           // 1,179,648
#define OFF_PO   OFF_XS
#define OFF_P1   OFF_XS
#define OFF_QB   (OFF_XS + SZ_XS)
#define SZ_QB    (NB*LL*CC)           // 1,179,648
#define OFF_VT   (OFF_QB + SZ_QB)
#define SZ_VT_F  (NB*CC*LL/2)         // bf16 buffer, 589,824 floats
#define OFF_AO   (OFF_VT + SZ_VT_F)   // pao0 during attn, ao after comb
#define SZ_AO    (NB*LL*CC)
#define OFF_EB   (OFF_AO + SZ_AO)
#define SZ_EB    (NB*HEADS*LL)
#define OFF_PTX  (OFF_EB + SZ_EB)
#define SZ_PT    (PTAB_N*CC)
#define OFF_PTY  (OFF_PTX + SZ_PT)
#define OFF_WB   (OFF_PTY + SZ_PT)
#define OFF_SS   (OFF_WB + HEADS*CC)
#define SZ_SS    (2*NB*HEADS*LL)      // 73,728

// ---------------- extract strided x ----------------
__global__ void k_extract(const float* __restrict__ x, float* __restrict__ xs) {
    int idx = blockIdx.x*256 + threadIdx.x;
    if (idx >= NB*CC*LL) return;
    int s = idx % LL; int c = (idx / LL) % CC; int n = idx / (CC*LL);
    int h = s / GG, w = s % GG;
    xs[idx] = x[((n*CC + c)*96 + 2*h)*96 + 2*w];
}

// ---------------- wb[i][c] = sum_d ab[i*32+d]*Wk[(i*32+d)][c] ----------------
__global__ void k_wb(const float* __restrict__ Wk, const float* __restrict__ ab,
                     float* __restrict__ wb) {
    int i = blockIdx.x; int c = threadIdx.x;
    float acc = 0.f;
    for (int d = 0; d < DD; ++d) acc += ab[i*DD+d] * Wk[(i*DD+d)*CC + c];
    wb[i*CC + c] = acc;
}

// ---------------- ptab[dd][o] = inv_s2 * sum_e emb(2*(dd-47))[e]*Wg[o][e] ----------------
__global__ void k_ptab(const float* __restrict__ Wgx, const float* __restrict__ Wgy,
                       float* __restrict__ ptx, float* __restrict__ pty) {
    __shared__ float emb[128];
    int ddv = blockIdx.x; int which = blockIdx.y;
    int t = threadIdx.x;
    float diff = 2.0f * (float)(ddv - 47);
    if (t < 64) {
        float dim = powf(1000.0f, (float)t / 64.0f);
        float ang = diff / dim;
        emb[t]      = sinf(ang);
        emb[t + 64] = cosf(ang);
    }
    __syncthreads();
    const float* Wg = which ? Wgy : Wgx;
    float* pt = which ? pty : ptx;
    float acc = 0.f;
    #pragma unroll 8
    for (int e = 0; e < 128; ++e) acc += emb[e] * Wg[t*128 + e];
    pt[ddv*CC + t] = acc * 0.70710678118654752f;
}

// ---------------- ebx[n][i][s] = exp(sum_c wb[i][c]*xs[n][c][s]) ----------------
__global__ void k_eb(const float* __restrict__ xs, const float* __restrict__ wb,
                     float* __restrict__ eb) {
    int s = blockIdx.x*256 + threadIdx.x;
    int n = blockIdx.y;
    float acc[HEADS] = {};
    const float* xp = xs + n*CC*LL + s;
    for (int c = 0; c < CC; ++c) {
        float xv = xp[c*LL];
        #pragma unroll
        for (int i = 0; i < HEADS; ++i) acc[i] += wb[i*CC+c] * xv;
    }
    #pragma unroll
    for (int i = 0; i < HEADS; ++i) eb[(n*HEADS+i)*LL + s] = __expf(acc[i]);
}

// ---------------- GEMM: [Wq;Wv](512x256) @ xs(256xL) ----------------
// Q rows (o<256)  -> qb[n][j][256] fp32
// V rows (o>=256) -> vtb[n][ch][2304] bf16 (transposed: kv contiguous)
__global__ __launch_bounds__(256) void k_gemm_qv(const float* __restrict__ Wq,
                                                 const float* __restrict__ Wv,
                                                 const float* __restrict__ xs,
                                                 float* __restrict__ qb,
                                                 __bf16* __restrict__ vtb) {
    const int n  = blockIdx.z;
    const int m0 = blockIdx.y * 64;
    const int j0 = blockIdx.x * 64;
    __shared__ float As[16*68];
    __shared__ float Bs[16*68];
    const int t = threadIdx.x;
    const float* B = xs + n*CC*LL;
    float acc[4][4] = {};
    const int ty = t >> 4, tx = t & 15;
    for (int k0 = 0; k0 < CC; k0 += 16) {
        {
            int m = t >> 2, kq = t & 3;
            int o = m0 + m;
            const float* Arow = (o < CC) ? (Wq + o*CC) : (Wv + (o-CC)*CC);
            float4 av = *(const float4*)(Arow + k0 + kq*4);
            As[(kq*4+0)*68 + m] = av.x;
            As[(kq*4+1)*68 + m] = av.y;
            As[(kq*4+2)*68 + m] = av.z;
            As[(kq*4+3)*68 + m] = av.w;
            int kb = t >> 4, n4 = t & 15;
            float4 bv = *(const float4*)(B + (k0+kb)*LL + j0 + n4*4);
            *(float4*)(&Bs[kb*68 + n4*4]) = bv;
        }
        __syncthreads();
        #pragma unroll
        for (int k = 0; k < 16; ++k) {
            float4 a = *(const float4*)(&As[k*68 + ty*4]);
            float4 b = *(const float4*)(&Bs[k*68 + tx*4]);
            float av[4] = {a.x,a.y,a.z,a.w};
            float bv[4] = {b.x,b.y,b.z,b.w};
            #pragma unroll
            for (int p = 0; p < 4; ++p)
                #pragma unroll
                for (int q = 0; q < 4; ++q) acc[p][q] += av[p]*bv[q];
        }
        __syncthreads();
    }
    if (m0 < CC) {
        #pragma unroll
        for (int p = 0; p < 4; ++p) {
            int o = m0 + ty*4 + p;
            #pragma unroll
            for (int q = 0; q < 4; ++q)
                qb[(size_t)(n*LL + j0 + tx*4 + q)*CC + o] = acc[p][q];
        }
    } else {
        #pragma unroll
        for (int p = 0; p < 4; ++p) {
            int ch = m0 - CC + ty*4 + p;   // 0..255 == i*32+d
            bf16x4 pk;
            pk[0] = (__bf16)acc[p][0];
            pk[1] = (__bf16)acc[p][1];
            pk[2] = (__bf16)acc[p][2];
            pk[3] = (__bf16)acc[p][3];
            *(bf16x4*)(vtb + (size_t)(n*CC + ch)*LL + j0 + tx*4) = pk;
        }
    }
}

// ---------------- attention: MFMA PV, factorized exp weights, 2-way kv split ----
// block = (n, i, 64 q-rows, kv-half). 4 waves, wave mw owns q-rows s0+mw*16..+16.
// A-frag: lane holds P[rq = mw*16 + (lane&15)][k-chunk (lane>>4)*8], in-register.
// B-frag: lane reads vtb[d0 + (lane&15)][k-chunk] (bf16x8, global/L2).
// Outputs UNNORMALIZED partial acc + partial S; k_comb combines halves.
__global__ __launch_bounds__(256) void k_attn(const float* __restrict__ qb,
                                              const __bf16* __restrict__ vtb,
                                              const float* __restrict__ ebx,
                                              const float* __restrict__ ptx,
                                              const float* __restrict__ pty,
                                              float* __restrict__ pao0,
                                              float* __restrict__ pao1,
                                              float* __restrict__ Sarr) {
    const int t = threadIdx.x;
    const int lane = t & 63;
    const int mw = t >> 6;
    const int n = blockIdx.y >> 3, i = blockIdx.y & 7;
    const int s0 = blockIdx.x * 64;
    const int half = blockIdx.z;
    const int u0 = half * 24;

    __shared__ float qs[64*32];
    __shared__ float Eys[64*25];   // exp(Ey) for this half's 24 u's, stride 25
    __shared__ float Exs[64*52];   // exp(Ex), stride 52 (16B-aligned rows)
    __shared__ float ebt[KVH];     // exp(e_bias), this half

    // stage Q tile (64 rows x 32 ch)
    #pragma unroll
    for (int l = 0; l < 2; ++l) {
        int f = t + 256*l;
        int r4 = f >> 3, dq = f & 7;
        float4 v4 = *(const float4*)(qb + (size_t)(n*LL + s0 + r4)*CC + i*32 + dq*4);
        *(float4*)(&qs[r4*32 + dq*4]) = v4;
    }
    __syncthreads();

    // phase 1: exp(Ey[r][u0+j]) (j<24), exp(Ex[r][v]) (v<48); also stage ebt
    for (int oidx = t; oidx < 64*72; oidx += 256) {
        int r = oidx / 72, j = oidx % 72;
        int s = s0 + r, h = s / GG, w = s % GG;
        int ddv; const float* tab;
        if (j < 24) { ddv = h - (u0 + j) + 47; tab = pty; }
        else        { ddv = w - (j-24) + 47;   tab = ptx; }
        const float4* tp = (const float4*)(tab + ddv*CC + i*32);
        const float4* qp = (const float4*)(qs + r*32);
        float acc = 0.f;
        #pragma unroll
        for (int d4 = 0; d4 < 8; ++d4) {
            float4 a = qp[d4]; float4 b = tp[d4];
            acc += a.x*b.x + a.y*b.y + a.z*b.z + a.w*b.w;
        }
        float e = __expf(acc);
        if (j < 24) Eys[r*25 + j] = e; else Exs[r*52 + (j-24)] = e;
    }
    {
        const float* ebg = ebx + (size_t)(n*HEADS + i)*LL + half*KVH;
        for (int f = t; f < KVH/4; f += 256)
            ((float4*)ebt)[f] = ((const float4*)ebg)[f];
    }
    __syncthreads();

    // main loop: zero barriers, 12 kv-tiles of 96
    const int r = lane & 15;
    const int g = lane >> 4;
    const int rq = mw*16 + r;          // block-relative q-row owned by this lane
    f32x4 acc0 = {0.f,0.f,0.f,0.f}, acc1 = {0.f,0.f,0.f,0.f};
    float S = 0.f;
    const __bf16* vp0 = vtb + (size_t)(n*CC + i*32 + r)*LL + half*KVH;
    const __bf16* vp1 = vp0 + (size_t)16*LL;
    const float* exrow = Exs + rq*52;
    const float* eyrow = Eys + rq*25;

    for (int tt = 0; tt < 12; ++tt) {
        float ey0 = eyrow[2*tt];
        float ey1 = eyrow[2*tt+1];
        int kbase = tt*96 + g*8;
        #pragma unroll
        for (int c = 0; c < 3; ++c) {
            int kl = kbase + c*32;
            float4 e0 = *(const float4*)(ebt + kl);
            float4 e1 = *(const float4*)(ebt + kl + 4);
            int vb; float ey;
            if (c == 0)      { vb = g*8;      ey = ey0; }
            else if (c == 2) { vb = 16 + g*8; ey = ey1; }
            else { vb = (g < 2) ? (32 + g*8) : ((g-2)*8);
                   ey = (g < 2) ? ey0 : ey1; }
            float4 x0 = *(const float4*)(exrow + vb);
            float4 x1 = *(const float4*)(exrow + vb + 4);
            float w0 = e0.x*x0.x*ey, w1 = e0.y*x0.y*ey;
            float w2 = e0.z*x0.z*ey, w3 = e0.w*x0.w*ey;
            float w4 = e1.x*x1.x*ey, w5 = e1.y*x1.y*ey;
            float w6 = e1.z*x1.z*ey, w7 = e1.w*x1.w*ey;
            S += ((w0+w1)+(w2+w3)) + ((w4+w5)+(w6+w7));
            bf16x8 av;
            av[0]=(__bf16)w0; av[1]=(__bf16)w1; av[2]=(__bf16)w2; av[3]=(__bf16)w3;
            av[4]=(__bf16)w4; av[5]=(__bf16)w5; av[6]=(__bf16)w6; av[7]=(__bf16)w7;
            bf16x8 b0 = *(const bf16x8*)(vp0 + kl);
            bf16x8 b1 = *(const bf16x8*)(vp1 + kl);
            acc0 = __builtin_amdgcn_mfma_f32_16x16x32_bf16(av, b0, acc0, 0, 0, 0);
            acc1 = __builtin_amdgcn_mfma_f32_16x16x32_bf16(av, b1, acc1, 0, 0, 0);
        }
    }

    // S: reduce over k-chunk groups (lanes 16 apart); every lane then has S[rq]
    S += __shfl_xor(S, 16, 64);
    S += __shfl_xor(S, 32, 64);

    float* pao = half ? pao1 : pao0;
    if (g == 0)
        Sarr[(size_t)half*NB*HEADS*LL + (size_t)(n*HEADS+i)*LL + s0 + mw*16 + r] = S;

    // D layout: row = g*4 + reg, col = lane&15 (+16 for acc1)
    #pragma unroll
    for (int reg = 0; reg < 4; ++reg) {
        int row = g*4 + reg;
        size_t base = (size_t)(n*LL + s0 + mw*16 + row)*CC + i*32;
        pao[base + r]      = acc0[reg];
        pao[base + 16 + r] = acc1[reg];
    }
}

// ---------------- combine kv halves: ao = (p0+p1)/(S0+S1) ----------------
__global__ void k_comb(const float* __restrict__ p0, const float* __restrict__ p1,
                       const float* __restrict__ Sarr, float* __restrict__ ao) {
    int idx = blockIdx.x*256 + threadIdx.x;   // float4 index, total NB*LL*CC/4
    const int NC4 = CC/4;
    int c4 = idx % NC4; int rest = idx / NC4; int s = rest % LL; int n = rest / LL;
    int i = c4 >> 3;
    float S0 = Sarr[(size_t)(n*HEADS+i)*LL + s];
    float S1 = Sarr[(size_t)NB*HEADS*LL + (size_t)(n*HEADS+i)*LL + s];
    float inv = 1.0f/(S0+S1);
    float4 a = ((const float4*)p0)[idx];
    float4 b = ((const float4*)p1)[idx];
    float4 o;
    o.x=(a.x+b.x)*inv; o.y=(a.y+b.y)*inv; o.z=(a.z+b.z)*inv; o.w=(a.w+b.w)*inv;
    ((float4*)ao)[idx] = o;
}

// ---------------- proj GEMM: Wproj(256x256) @ ao^T -> po[n][o][s] ----------------
__global__ __launch_bounds__(256) void k_gemm_proj(const float* __restrict__ Wp,
                                                   const float* __restrict__ ao,
                                                   float* __restrict__ po) {
    const int n  = blockIdx.z;
    const int m0 = blockIdx.y * 64;
    const int j0 = blockIdx.x * 64;
    __shared__ float As[16*68];
    __shared__ float Bs[16*68];
    const int t = threadIdx.x;
    const float* Bt = ao + (size_t)n*LL*CC;   // [j][k]
    float acc[4][4] = {};
    const int ty = t >> 4, tx = t & 15;
    for (int k0 = 0; k0 < CC; k0 += 16) {
        {
            int m = t >> 2, kq = t & 3;
            float4 av = *(const float4*)(Wp + (m0+m)*CC + k0 + kq*4);
            As[(kq*4+0)*68 + m] = av.x;
            As[(kq*4+1)*68 + m] = av.y;
            As[(kq*4+2)*68 + m] = av.z;
            As[(kq*4+3)*68 + m] = av.w;
            float4 bv = *(const float4*)(Bt + (size_t)(j0+m)*CC + k0 + kq*4);
            Bs[(kq*4+0)*68 + m] = bv.x;
            Bs[(kq*4+1)*68 + m] = bv.y;
            Bs[(kq*4+2)*68 + m] = bv.z;
            Bs[(kq*4+3)*68 + m] = bv.w;
        }
        __syncthreads();
        #pragma unroll
        for (int k = 0; k < 16; ++k) {
            float4 a = *(const float4*)(&As[k*68 + ty*4]);
            float4 b = *(const float4*)(&Bs[k*68 + tx*4]);
            float av[4] = {a.x,a.y,a.z,a.w};
            float bv[4] = {b.x,b.y,b.z,b.w};
            #pragma unroll
            for (int p = 0; p < 4; ++p)
                #pragma unroll
                for (int q = 0; q < 4; ++q) acc[p][q] += av[p]*bv[q];
        }
        __syncthreads();
    }
    #pragma unroll
    for (int p = 0; p < 4; ++p) {
        int o = m0 + ty*4 + p;
        float4 ov = make_float4(acc[p][0],acc[p][1],acc[p][2],acc[p][3]);
        *(float4*)(po + (size_t)n*CC*LL + (size_t)o*LL + j0 + tx*4) = ov;
    }
}

// ---------------- bilinear x2 upsample + bias + gamma + residual ----------------
__global__ void k_final(const float* __restrict__ x, const float* __restrict__ po,
                        const float* __restrict__ bproj, const float* __restrict__ gammap,
                        float* __restrict__ out) {
    int idx = blockIdx.x*256 + threadIdx.x;
    if (idx >= NB*CC*96*96) return;
    int X = idx % 96, Y = (idx/96) % 96, o = (idx/(96*96)) % CC, n = idx/(96*96*CC);
    float gamma = gammap[0];
    float yf = Y*0.5f - 0.25f, xf = X*0.5f - 0.25f;
    float y0f = floorf(yf), x0f = floorf(xf);
    float tyy = yf - y0f, txx = xf - x0f;
    int y0 = (int)y0f, x0 = (int)x0f;
    int iy0 = max(y0,0), iy1 = min(y0+1,GG-1);
    int ix0 = max(x0,0), ix1 = min(x0+1,GG-1);
    const float* pp = po + (size_t)(n*CC + o)*LL;
    float v00 = pp[iy0*GG+ix0], v01 = pp[iy0*GG+ix1];
    float v10 = pp[iy1*GG+ix0], v11 = pp[iy1*GG+ix1];
    float vy0 = v00 + txx*(v01-v00);
    float vy1 = v10 + txx*(v11-v10);
    float bil = vy0 + tyy*(vy1-vy0);
    out[idx] = gamma*(bil + bproj[o]) + x[idx];
}

extern "C" void kernel_launch(void* const* d_in, const int* in_sizes, int n_in,
                              void* d_out, int out_size, void* d_ws, size_t ws_size,
                              hipStream_t stream) {
    const float* x   = (const float*)d_in[0];
    const float* Wq  = (const float*)d_in[1];
    const float* Wk  = (const float*)d_in[2];
    const float* Wv  = (const float*)d_in[3];
    const float* Wgx = (const float*)d_in[4];
    const float* Wgy = (const float*)d_in[5];
    const float* ab  = (const float*)d_in[6];
    const float* Wp  = (const float*)d_in[7];
    const float* bp  = (const float*)d_in[8];
    const float* gm  = (const float*)d_in[9];
    float* ws = (float*)d_ws;
    float* xs  = ws + OFF_XS;
    float* qbp = ws + OFF_QB;
    __bf16* vtb = (__bf16*)(ws + OFF_VT);
    float* aop = ws + OFF_AO;      // pao0 during attn, ao after comb
    float* p1p = ws + OFF_P1;      // pao1 (aliases xs)
    float* ebp = ws + OFF_EB;
    float* ptxp= ws + OFF_PTX;
    float* ptyp= ws + OFF_PTY;
    float* wbp = ws + OFF_WB;
    float* ssp = ws + OFF_SS;
    float* pop = ws + OFF_PO;
    float* out = (float*)d_out;

    k_extract<<<(NB*CC*LL + 255)/256, 256, 0, stream>>>(x, xs);
    k_wb<<<HEADS, 256, 0, stream>>>(Wk, ab, wbp);
    k_ptab<<<dim3(PTAB_N, 2), 256, 0, stream>>>(Wgx, Wgy, ptxp, ptyp);
    k_eb<<<dim3(LL/256, NB), 256, 0, stream>>>(xs, wbp, ebp);
    k_gemm_qv<<<dim3(LL/64, 8, NB), 256, 0, stream>>>(Wq, Wv, xs, qbp, vtb);
    k_attn<<<dim3(LL/64, NB*HEADS, 2), 256, 0, stream>>>(qbp, vtb, ebp, ptxp, ptyp,
                                                         aop, p1p, ssp);
    k_comb<<<NB*LL*CC/4/256, 256, 0, stream>>>(aop, p1p, ssp, aop);
    k_gemm_proj<<<dim3(LL/64, 4, NB), 256, 0, stream>>>(Wp, aop, pop);
    k_final<<<(NB*CC*96*96 + 255)/256, 256, 0, stream>>>(x, pop, bp, gm, out);
}

// Round 6
// 205.528 us; speedup vs baseline: 1.2064x; 1.2064x over previous
//
#include <hip/hip_runtime.h>
#include <math.h>

#define CC 256
#define HEADS 8
#define DD 32
#define GG 48
#define LL (GG*GG)      // 2304
#define NB 2
#define PTAB_N 95
#define KVH 1152        // kv rows per half

typedef float f32x4 __attribute__((ext_vector_type(4)));
typedef __bf16 bf16x8 __attribute__((ext_vector_type(8)));
typedef __bf16 bf16x4 __attribute__((ext_vector_type(4)));

// workspace layout (floats).
// pao1 aliases xs (dead after gemm_qv/eb). po aliases qb (dead after attn).
#define OFF_XS   0
#define SZ_XS    (NB*CC*LL)           // 1,179,648
#define OFF_P1   OFF_XS
#define OFF_QB   (OFF_XS + SZ_XS)
#define SZ_QB    (NB*LL*CC)           // 1,179,648
#define OFF_PO   OFF_QB
#define OFF_VT   (OFF_QB + SZ_QB)
#define SZ_VT_F  (NB*CC*LL/2)         // bf16 buffer, 589,824 floats
#define OFF_AO   (OFF_VT + SZ_VT_F)   // pao0
#define SZ_AO    (NB*LL*CC)
#define OFF_EB   (OFF_AO + SZ_AO)
#define SZ_EB    (NB*HEADS*LL)
#define OFF_PTX  (OFF_EB + SZ_EB)
#define SZ_PT    (PTAB_N*CC)
#define OFF_PTY  (OFF_PTX + SZ_PT)
#define OFF_WB   (OFF_PTY + SZ_PT)
#define OFF_SS   (OFF_WB + HEADS*CC)
#define SZ_SS    (2*NB*HEADS*LL)      // 73,728

// ---------------- extract strided x ----------------
__global__ void k_extract(const float* __restrict__ x, float* __restrict__ xs) {
    int idx = blockIdx.x*256 + threadIdx.x;
    if (idx >= NB*CC*LL) return;
    int s = idx % LL; int c = (idx / LL) % CC; int n = idx / (CC*LL);
    int h = s / GG, w = s % GG;
    xs[idx] = x[((n*CC + c)*96 + 2*h)*96 + 2*w];
}

// ---------------- wb[i][c] = sum_d ab[i*32+d]*Wk[(i*32+d)][c] ----------------
__global__ void k_wb(const float* __restrict__ Wk, const float* __restrict__ ab,
                     float* __restrict__ wb) {
    int i = blockIdx.x; int c = threadIdx.x;
    float acc = 0.f;
    for (int d = 0; d < DD; ++d) acc += ab[i*DD+d] * Wk[(i*DD+d)*CC + c];
    wb[i*CC + c] = acc;
}

// ---------------- ptab[dd][o] = inv_s2 * sum_e emb(2*(dd-47))[e]*Wg[o][e] ----------------
__global__ void k_ptab(const float* __restrict__ Wgx, const float* __restrict__ Wgy,
                       float* __restrict__ ptx, float* __restrict__ pty) {
    __shared__ float emb[128];
    int ddv = blockIdx.x; int which = blockIdx.y;
    int t = threadIdx.x;
    float diff = 2.0f * (float)(ddv - 47);
    if (t < 64) {
        float dim = powf(1000.0f, (float)t / 64.0f);
        float ang = diff / dim;
        emb[t]      = sinf(ang);
        emb[t + 64] = cosf(ang);
    }
    __syncthreads();
    const float* Wg = which ? Wgy : Wgx;
    float* pt = which ? pty : ptx;
    float acc = 0.f;
    #pragma unroll 8
    for (int e = 0; e < 128; ++e) acc += emb[e] * Wg[t*128 + e];
    pt[ddv*CC + t] = acc * 0.70710678118654752f;
}

// ---------------- ebx[n][i][s] = exp(sum_c wb[i][c]*xs[n][c][s]) ----------------
__global__ void k_eb(const float* __restrict__ xs, const float* __restrict__ wb,
                     float* __restrict__ eb) {
    int s = blockIdx.x*256 + threadIdx.x;
    int n = blockIdx.y;
    float acc[HEADS] = {};
    const float* xp = xs + n*CC*LL + s;
    for (int c = 0; c < CC; ++c) {
        float xv = xp[c*LL];
        #pragma unroll
        for (int i = 0; i < HEADS; ++i) acc[i] += wb[i*CC+c] * xv;
    }
    #pragma unroll
    for (int i = 0; i < HEADS; ++i) eb[(n*HEADS+i)*LL + s] = __expf(acc[i]);
}

// ---------------- GEMM: [Wq;Wv](512x256) @ xs(256xL) ----------------
__global__ __launch_bounds__(256) void k_gemm_qv(const float* __restrict__ Wq,
                                                 const float* __restrict__ Wv,
                                                 const float* __restrict__ xs,
                                                 float* __restrict__ qb,
                                                 __bf16* __restrict__ vtb) {
    const int n  = blockIdx.z;
    const int m0 = blockIdx.y * 64;
    const int j0 = blockIdx.x * 64;
    __shared__ float As[16*68];
    __shared__ float Bs[16*68];
    const int t = threadIdx.x;
    const float* B = xs + n*CC*LL;
    float acc[4][4] = {};
    const int ty = t >> 4, tx = t & 15;
    for (int k0 = 0; k0 < CC; k0 += 16) {
        {
            int m = t >> 2, kq = t & 3;
            int o = m0 + m;
            const float* Arow = (o < CC) ? (Wq + o*CC) : (Wv + (o-CC)*CC);
            float4 av = *(const float4*)(Arow + k0 + kq*4);
            As[(kq*4+0)*68 + m] = av.x;
            As[(kq*4+1)*68 + m] = av.y;
            As[(kq*4+2)*68 + m] = av.z;
            As[(kq*4+3)*68 + m] = av.w;
            int kb = t >> 4, n4 = t & 15;
            float4 bv = *(const float4*)(B + (k0+kb)*LL + j0 + n4*4);
            *(float4*)(&Bs[kb*68 + n4*4]) = bv;
        }
        __syncthreads();
        #pragma unroll
        for (int k = 0; k < 16; ++k) {
            float4 a = *(const float4*)(&As[k*68 + ty*4]);
            float4 b = *(const float4*)(&Bs[k*68 + tx*4]);
            float av[4] = {a.x,a.y,a.z,a.w};
            float bv[4] = {b.x,b.y,b.z,b.w};
            #pragma unroll
            for (int p = 0; p < 4; ++p)
                #pragma unroll
                for (int q = 0; q < 4; ++q) acc[p][q] += av[p]*bv[q];
        }
        __syncthreads();
    }
    if (m0 < CC) {
        #pragma unroll
        for (int p = 0; p < 4; ++p) {
            int o = m0 + ty*4 + p;
            #pragma unroll
            for (int q = 0; q < 4; ++q)
                qb[(size_t)(n*LL + j0 + tx*4 + q)*CC + o] = acc[p][q];
        }
    } else {
        #pragma unroll
        for (int p = 0; p < 4; ++p) {
            int ch = m0 - CC + ty*4 + p;   // 0..255 == i*32+d
            bf16x4 pk;
            pk[0] = (__bf16)acc[p][0];
            pk[1] = (__bf16)acc[p][1];
            pk[2] = (__bf16)acc[p][2];
            pk[3] = (__bf16)acc[p][3];
            *(bf16x4*)(vtb + (size_t)(n*CC + ch)*LL + j0 + tx*4) = pk;
        }
    }
}

__device__ __forceinline__ float4 mul4s(float4 a, float s) {
    return make_float4(a.x*s, a.y*s, a.z*s, a.w*s);
}

// ---------------- attention: MFMA PV, LDS-dbuf V, Ex-in-registers ----------------
// block = (n, i, 64 q-rows, kv-half). 4 waves; wave mw owns q-rows s0+mw*16..+16.
// A-frag (weights) built in-register; B-frag (V) via ds_read_b128 from dbuf tile.
// Outputs UNNORMALIZED partial acc + partial S; gemm_proj combines halves.
__global__ __launch_bounds__(256) void k_attn(const float* __restrict__ qb,
                                              const __bf16* __restrict__ vtb,
                                              const float* __restrict__ ebx,
                                              const float* __restrict__ ptx,
                                              const float* __restrict__ pty,
                                              float* __restrict__ pao0,
                                              float* __restrict__ pao1,
                                              float* __restrict__ Sarr) {
    const int t = threadIdx.x;
    const int lane = t & 63;
    const int mw = t >> 6;
    const int n = blockIdx.y >> 3, i = blockIdx.y & 7;
    const int s0 = blockIdx.x * 64;
    const int half = blockIdx.z;
    const int u0 = half * 24;

    // LDS pool (dw): [0,2048) qs | [2048,5376) Exs  -- phases 0-1
    //                [0,3328) Vt dbuf 2x32x52dw bf16 | [3328,4480) ebt -- main
    //                [5376,6976) Eys (persistent)
    __shared__ float smem[6976];
    float* qs  = smem;             // [64*32]
    float* Exs = smem + 2048;      // [64][52]
    float* ebt = smem + 3328;      // [1152]
    float* Eys = smem + 5376;      // [64][25]

    // phase 0: stage Q tile (64 rows x 32 ch)
    #pragma unroll
    for (int l = 0; l < 2; ++l) {
        int f = t + 256*l;
        int r4 = f >> 3, dq = f & 7;
        float4 v4 = *(const float4*)(qb + (size_t)(n*LL + s0 + r4)*CC + i*32 + dq*4);
        *(float4*)(&qs[r4*32 + dq*4]) = v4;
    }
    __syncthreads();

    // phase 1: exp(Ey[r][u0+j]) (j<24) -> Eys; exp(Ex[r][v]) (v<48) -> Exs
    for (int oidx = t; oidx < 64*72; oidx += 256) {
        int r = oidx / 72, j = oidx % 72;
        int s = s0 + r, h = s / GG, w = s % GG;
        int ddv; const float* tab;
        if (j < 24) { ddv = h - (u0 + j) + 47; tab = pty; }
        else        { ddv = w - (j-24) + 47;   tab = ptx; }
        const float4* tp = (const float4*)(tab + ddv*CC + i*32);
        const float4* qp = (const float4*)(qs + r*32);
        float acc = 0.f;
        #pragma unroll
        for (int d4 = 0; d4 < 8; ++d4) {
            float4 a = qp[d4]; float4 b = tp[d4];
            acc += a.x*b.x + a.y*b.y + a.z*b.z + a.w*b.w;
        }
        float e = __expf(acc);
        if (j < 24) Eys[r*25 + j] = e; else Exs[r*52 + (j-24)] = e;
    }
    __syncthreads();

    // load per-lane Ex factors into named registers (static indexing)
    const int r = lane & 15, g = lane >> 4;
    const int rq = mw*16 + r;
    const int vb0 = g*8;
    const int vb1 = (g < 2) ? (32 + g*8) : ((g-2)*8);
    const int vb2 = 16 + g*8;
    const float* exr = Exs + rq*52;
    float4 xr0a = *(const float4*)(exr + vb0);
    float4 xr0b = *(const float4*)(exr + vb0 + 4);
    float4 xr1a = *(const float4*)(exr + vb1);
    float4 xr1b = *(const float4*)(exr + vb1 + 4);
    float4 xr2a = *(const float4*)(exr + vb2);
    float4 xr2b = *(const float4*)(exr + vb2 + 4);
    __syncthreads();   // Exs/qs consumed; region reusable

    // stage exp(e_bias) + V tile 0
    const float* ebg = ebx + (size_t)(n*HEADS + i)*LL + half*KVH;
    for (int f = t; f < KVH/4; f += 256)
        ((float4*)ebt)[f] = ((const float4*)ebg)[f];
    const __bf16* vgb = vtb + (size_t)(n*CC + i*32)*LL + half*KVH;
    {
        int ch = t/12, part = t%12;
        float4 v = *(const float4*)(vgb + (size_t)ch*LL + part*8);
        *(float4*)(smem + ch*52 + part*4) = v;
        if (t < 128) {
            int i1 = t+256, ch1 = i1/12, p1 = i1%12;
            float4 v1 = *(const float4*)(vgb + (size_t)ch1*LL + p1*8);
            *(float4*)(smem + ch1*52 + p1*4) = v1;
        }
    }
    __syncthreads();

    // main loop: 12 kv-tiles of 96, double-buffered
    f32x4 acc0 = {0.f,0.f,0.f,0.f}, acc1 = {0.f,0.f,0.f,0.f};
    float S = 0.f;
    const int ch_s = t/12, pt_s = t%12;
    const int i1 = t+256, ch1_s = i1/12, pt1_s = i1%12;

    for (int tt = 0; tt < 12; ++tt) {
        const int buf = tt & 1;
        // prefetch next tile into registers (issue before compute)
        float4 gv0, gv1;
        if (tt < 11) {
            gv0 = *(const float4*)(vgb + (size_t)ch_s*LL + (tt+1)*96 + pt_s*8);
            if (t < 128)
                gv1 = *(const float4*)(vgb + (size_t)ch1_s*LL + (tt+1)*96 + pt1_s*8);
        }
        // per-tile ey folding
        float ey0 = Eys[rq*25 + 2*tt];
        float ey1 = Eys[rq*25 + 2*tt + 1];
        float eyB = (g < 2) ? ey0 : ey1;
        float4 xe0a = mul4s(xr0a, ey0), xe0b = mul4s(xr0b, ey0);
        float4 xe1a = mul4s(xr1a, eyB), xe1b = mul4s(xr1b, eyB);
        float4 xe2a = mul4s(xr2a, ey1), xe2b = mul4s(xr2b, ey1);

        #pragma unroll
        for (int c = 0; c < 3; ++c) {
            const float* ep = ebt + tt*96 + c*32 + g*8;
            float4 e0 = *(const float4*)ep;
            float4 e1 = *(const float4*)(ep + 4);
            float4 xa = (c == 0) ? xe0a : (c == 1) ? xe1a : xe2a;
            float4 xb = (c == 0) ? xe0b : (c == 1) ? xe1b : xe2b;
            float w0 = e0.x*xa.x, w1 = e0.y*xa.y, w2 = e0.z*xa.z, w3 = e0.w*xa.w;
            float w4 = e1.x*xb.x, w5 = e1.y*xb.y, w6 = e1.z*xb.z, w7 = e1.w*xb.w;
            S += ((w0+w1)+(w2+w3)) + ((w4+w5)+(w6+w7));
            bf16x8 av;
            av[0]=(__bf16)w0; av[1]=(__bf16)w1; av[2]=(__bf16)w2; av[3]=(__bf16)w3;
            av[4]=(__bf16)w4; av[5]=(__bf16)w5; av[6]=(__bf16)w6; av[7]=(__bf16)w7;
            const int dwb = buf*1664 + c*16 + g*4;
            bf16x8 b0 = *(const bf16x8*)(smem + dwb + r*52);
            bf16x8 b1 = *(const bf16x8*)(smem + dwb + (16+r)*52);
            acc0 = __builtin_amdgcn_mfma_f32_16x16x32_bf16(av, b0, acc0, 0, 0, 0);
            acc1 = __builtin_amdgcn_mfma_f32_16x16x32_bf16(av, b1, acc1, 0, 0, 0);
        }
        // write staged tile, one barrier per iteration
        if (tt < 11) {
            const int wb = (buf^1)*1664;
            *(float4*)(smem + wb + ch_s*52 + pt_s*4) = gv0;
            if (t < 128)
                *(float4*)(smem + wb + ch1_s*52 + pt1_s*4) = gv1;
            __syncthreads();
        }
    }

    // S: reduce over k-chunk groups (lanes 16 apart)
    S += __shfl_xor(S, 16, 64);
    S += __shfl_xor(S, 32, 64);

    float* pao = half ? pao1 : pao0;
    if (g == 0)
        Sarr[(size_t)half*NB*HEADS*LL + (size_t)(n*HEADS+i)*LL + s0 + mw*16 + r] = S;

    // D layout: row = g*4 + reg, col = lane&15 (+16 for acc1)
    #pragma unroll
    for (int reg = 0; reg < 4; ++reg) {
        int row = g*4 + reg;
        size_t base = (size_t)(n*LL + s0 + mw*16 + row)*CC + i*32;
        pao[base + r]      = acc0[reg];
        pao[base + 16 + r] = acc1[reg];
    }
}

// ---------------- proj GEMM with fused half-combine ----------------
// B[j][k] = (p0[j][k]+p1[j][k]) / (S0[i(k)][j]+S1[i(k)][j])
__global__ __launch_bounds__(256) void k_gemm_proj(const float* __restrict__ Wp,
                                                   const float* __restrict__ p0,
                                                   const float* __restrict__ p1,
                                                   const float* __restrict__ Sarr,
                                                   float* __restrict__ po) {
    const int n  = blockIdx.z;
    const int m0 = blockIdx.y * 64;
    const int j0 = blockIdx.x * 64;
    __shared__ float As[16*68];
    __shared__ float Bs[16*68];
    const int t = threadIdx.x;
    float acc[4][4] = {};
    const int ty = t >> 4, tx = t & 15;
    const int m = t >> 2, kq = t & 3;
    for (int k0 = 0; k0 < CC; k0 += 16) {
        {
            float4 av = *(const float4*)(Wp + (m0+m)*CC + k0 + kq*4);
            As[(kq*4+0)*68 + m] = av.x;
            As[(kq*4+1)*68 + m] = av.y;
            As[(kq*4+2)*68 + m] = av.z;
            As[(kq*4+3)*68 + m] = av.w;
            int k = k0 + kq*4;
            int ih = k >> 5;
            size_t bidx = (size_t)(n*LL + j0 + m)*CC + k;
            float4 b0 = *(const float4*)(p0 + bidx);
            float4 b1 = *(const float4*)(p1 + bidx);
            float S0 = Sarr[(size_t)(n*HEADS+ih)*LL + j0 + m];
            float S1 = Sarr[(size_t)NB*HEADS*LL + (size_t)(n*HEADS+ih)*LL + j0 + m];
            float inv = 1.0f/(S0+S1);
            Bs[(kq*4+0)*68 + m] = (b0.x+b1.x)*inv;
            Bs[(kq*4+1)*68 + m] = (b0.y+b1.y)*inv;
            Bs[(kq*4+2)*68 + m] = (b0.z+b1.z)*inv;
            Bs[(kq*4+3)*68 + m] = (b0.w+b1.w)*inv;
        }
        __syncthreads();
        #pragma unroll
        for (int k = 0; k < 16; ++k) {
            float4 a = *(const float4*)(&As[k*68 + ty*4]);
            float4 b = *(const float4*)(&Bs[k*68 + tx*4]);
            float av[4] = {a.x,a.y,a.z,a.w};
            float bv[4] = {b.x,b.y,b.z,b.w};
            #pragma unroll
            for (int p = 0; p < 4; ++p)
                #pragma unroll
                for (int q = 0; q < 4; ++q) acc[p][q] += av[p]*bv[q];
        }
        __syncthreads();
    }
    #pragma unroll
    for (int p = 0; p < 4; ++p) {
        int o = m0 + ty*4 + p;
        float4 ov = make_float4(acc[p][0],acc[p][1],acc[p][2],acc[p][3]);
        *(float4*)(po + (size_t)n*CC*LL + (size_t)o*LL + j0 + tx*4) = ov;
    }
}

// ---------------- bilinear x2 upsample + bias + gamma + residual ----------------
__global__ void k_final(const float* __restrict__ x, const float* __restrict__ po,
                        const float* __restrict__ bproj, const float* __restrict__ gammap,
                        float* __restrict__ out) {
    int idx = blockIdx.x*256 + threadIdx.x;
    if (idx >= NB*CC*96*96) return;
    int X = idx % 96, Y = (idx/96) % 96, o = (idx/(96*96)) % CC, n = idx/(96*96*CC);
    float gamma = gammap[0];
    float yf = Y*0.5f - 0.25f, xf = X*0.5f - 0.25f;
    float y0f = floorf(yf), x0f = floorf(xf);
    float tyy = yf - y0f, txx = xf - x0f;
    int y0 = (int)y0f, x0 = (int)x0f;
    int iy0 = max(y0,0), iy1 = min(y0+1,GG-1);
    int ix0 = max(x0,0), ix1 = min(x0+1,GG-1);
    const float* pp = po + (size_t)(n*CC + o)*LL;
    float v00 = pp[iy0*GG+ix0], v01 = pp[iy0*GG+ix1];
    float v10 = pp[iy1*GG+ix0], v11 = pp[iy1*GG+ix1];
    float vy0 = v00 + txx*(v01-v00);
    float vy1 = v10 + txx*(v11-v10);
    float bil = vy0 + tyy*(vy1-vy0);
    out[idx] = gamma*(bil + bproj[o]) + x[idx];
}

extern "C" void kernel_launch(void* const* d_in, const int* in_sizes, int n_in,
                              void* d_out, int out_size, void* d_ws, size_t ws_size,
                              hipStream_t stream) {
    const float* x   = (const float*)d_in[0];
    const float* Wq  = (const float*)d_in[1];
    const float* Wk  = (const float*)d_in[2];
    const float* Wv  = (const float*)d_in[3];
    const float* Wgx = (const float*)d_in[4];
    const float* Wgy = (const float*)d_in[5];
    const float* ab  = (const float*)d_in[6];
    const float* Wp  = (const float*)d_in[7];
    const float* bp  = (const float*)d_in[8];
    const float* gm  = (const float*)d_in[9];
    float* ws = (float*)d_ws;
    float* xs  = ws + OFF_XS;
    float* qbp = ws + OFF_QB;
    __bf16* vtb = (__bf16*)(ws + OFF_VT);
    float* aop = ws + OFF_AO;      // pao0
    float* p1p = ws + OFF_P1;      // pao1 (aliases xs)
    float* ebp = ws + OFF_EB;
    float* ptxp= ws + OFF_PTX;
    float* ptyp= ws + OFF_PTY;
    float* wbp = ws + OFF_WB;
    float* ssp = ws + OFF_SS;
    float* pop = ws + OFF_PO;      // aliases qb
    float* out = (float*)d_out;

    k_extract<<<(NB*CC*LL + 255)/256, 256, 0, stream>>>(x, xs);
    k_wb<<<HEADS, 256, 0, stream>>>(Wk, ab, wbp);
    k_ptab<<<dim3(PTAB_N, 2), 256, 0, stream>>>(Wgx, Wgy, ptxp, ptyp);
    k_eb<<<dim3(LL/256, NB), 256, 0, stream>>>(xs, wbp, ebp);
    k_gemm_qv<<<dim3(LL/64, 8, NB), 256, 0, stream>>>(Wq, Wv, xs, qbp, vtb);
    k_attn<<<dim3(LL/64, NB*HEADS, 2), 256, 0, stream>>>(qbp, vtb, ebp, ptxp, ptyp,
                                                         aop, p1p, ssp);
    k_gemm_proj<<<dim3(LL/64, 4, NB), 256, 0, stream>>>(Wp, aop, p1p, ssp, pop);
    k_final<<<(NB*CC*96*96 + 255)/256, 256, 0, stream>>>(x, pop, bp, gm, out);
}